// Round 8
// baseline (83.426 us; speedup 1.0000x reference)
//
#include <hip/hip_runtime.h>

#define N 64
#define MARGIN 0.1f
#define WAVES_PER_BLOCK 4
#define NBLOCKS 2048

// closed form (verified R2..R18, absmax 0.0): row_loss = sum_e u_e*(q_e - p_e)
//   p_e = #{k: lab_k < lab_e},  u_e = sc_e - MARGIN*p_e,  q_e = #{k: u_k < u_e}
//
// R19: 4-row straight-line batch per wave (rows = 4 * nwaves exactly).
//   R11 (80.2) and R18 (80.9) share the per-row shape: 1 row in flight,
//   1 lgkm drain + LDS round-trip per ~530 instrs, load latency exposed
//   per row. Both land at partial ~30us vs ~14us VALU-issue floor.
//   R19 batches the proven R11 compute form 4 rows wide:
//     - 8 per-lane loads issued together (fill sweep evicts L2/L3 each
//       iteration -> ~900cy misses; batching overlaps them),
//     - 4 interleaved pass-1 streams = 16 independent sign-bit chains,
//     - 4 ds_writes, ONE drain per wave (was 4),
//     - 4 interleaved pass-2 streams = 64 independent uniform ds_reads.
//   No new compute forms (R13/14/17 lesson), no launch-bounds clamp
//   (R15 lesson), no LDS pass-1 (R16 lesson).

__global__ __launch_bounds__(256) void mmrl_partial(const float* __restrict__ scores,
                                                    const float* __restrict__ labels,
                                                    float* __restrict__ partial,
                                                    int rows) {
    __shared__ float ubuf[WAVES_PER_BLOCK][4][N];   // 4 KB / block
    __shared__ float wsum[WAVES_PER_BLOCK];

    const int lane = threadIdx.x & 63;
    const int w    = threadIdx.x >> 6;
    const int gwave = blockIdx.x * WAVES_PER_BLOCK + w;
    const int nwaves = NBLOCKS * WAVES_PER_BLOCK;

    float acc = 0.0f;

    int row = gwave;

    // ---- 4-row batch (each wave runs this exactly once for rows=32768) ----
    for (; row + 3 * nwaves < rows; row += 4 * nwaves) {
        const int b0 = __builtin_amdgcn_readfirstlane(row) * N;
        const int b1 = b0 + nwaves * N;
        const int b2 = b1 + nwaves * N;
        const int b3 = b2 + nwaves * N;

        // 8 per-lane coalesced loads, all independent -> latencies overlap
        const float labv0 = labels[b0 + lane];
        const float labv1 = labels[b1 + lane];
        const float labv2 = labels[b2 + lane];
        const float labv3 = labels[b3 + lane];
        const float scv0  = scores[b0 + lane];
        const float scv1  = scores[b1 + lane];
        const float scv2  = scores[b2 + lane];
        const float scv3  = scores[b3 + lane];

        // ---- pass 1 x4: label ranks, 16 independent sign-bit chains ----
        const float4* L0 = (const float4*)(labels + b0);
        const float4* L1 = (const float4*)(labels + b1);
        const float4* L2 = (const float4*)(labels + b2);
        const float4* L3 = (const float4*)(labels + b3);
        int p00 = 0, p01 = 0, p02 = 0, p03 = 0;
        int p10 = 0, p11 = 0, p12 = 0, p13 = 0;
        int p20 = 0, p21 = 0, p22 = 0, p23 = 0;
        int p30 = 0, p31 = 0, p32 = 0, p33 = 0;
        #pragma unroll
        for (int kk = 0; kk < N / 4; ++kk) {
            const float4 a0 = L0[kk];
            p00 += __float_as_int(a0.x - labv0) >> 31;
            p01 += __float_as_int(a0.y - labv0) >> 31;
            p02 += __float_as_int(a0.z - labv0) >> 31;
            p03 += __float_as_int(a0.w - labv0) >> 31;
            const float4 a1 = L1[kk];
            p10 += __float_as_int(a1.x - labv1) >> 31;
            p11 += __float_as_int(a1.y - labv1) >> 31;
            p12 += __float_as_int(a1.z - labv1) >> 31;
            p13 += __float_as_int(a1.w - labv1) >> 31;
            const float4 a2 = L2[kk];
            p20 += __float_as_int(a2.x - labv2) >> 31;
            p21 += __float_as_int(a2.y - labv2) >> 31;
            p22 += __float_as_int(a2.z - labv2) >> 31;
            p23 += __float_as_int(a2.w - labv2) >> 31;
            const float4 a3 = L3[kk];
            p30 += __float_as_int(a3.x - labv3) >> 31;
            p31 += __float_as_int(a3.y - labv3) >> 31;
            p32 += __float_as_int(a3.z - labv3) >> 31;
            p33 += __float_as_int(a3.w - labv3) >> 31;
        }
        const int pv0 = -((p00 + p01) + (p02 + p03));
        const int pv1 = -((p10 + p11) + (p12 + p13));
        const int pv2 = -((p20 + p21) + (p22 + p23));
        const int pv3 = -((p30 + p31) + (p32 + p33));

        const float u0 = fmaf(-MARGIN, (float)pv0, scv0);
        const float u1 = fmaf(-MARGIN, (float)pv1, scv1);
        const float u2 = fmaf(-MARGIN, (float)pv2, scv2);
        const float u3 = fmaf(-MARGIN, (float)pv3, scv3);

        // ---- stage u x4, ONE drain for the whole batch ----
        ubuf[w][0][lane] = u0;
        ubuf[w][1][lane] = u1;
        ubuf[w][2][lane] = u2;
        ubuf[w][3][lane] = u3;
        asm volatile("s_waitcnt lgkmcnt(0)" ::: "memory");  // intra-wave LDS RAW

        // ---- pass 2 x4: u ranks, 64 independent uniform ds_reads ----
        const float4* U0 = (const float4*)ubuf[w][0];
        const float4* U1 = (const float4*)ubuf[w][1];
        const float4* U2 = (const float4*)ubuf[w][2];
        const float4* U3 = (const float4*)ubuf[w][3];
        int q00 = 0, q01 = 0, q02 = 0, q03 = 0;
        int q10 = 0, q11 = 0, q12 = 0, q13 = 0;
        int q20 = 0, q21 = 0, q22 = 0, q23 = 0;
        int q30 = 0, q31 = 0, q32 = 0, q33 = 0;
        #pragma unroll
        for (int kk = 0; kk < N / 4; ++kk) {
            const float4 c0 = U0[kk];
            q00 += __float_as_int(c0.x - u0) >> 31;
            q01 += __float_as_int(c0.y - u0) >> 31;
            q02 += __float_as_int(c0.z - u0) >> 31;
            q03 += __float_as_int(c0.w - u0) >> 31;
            const float4 c1 = U1[kk];
            q10 += __float_as_int(c1.x - u1) >> 31;
            q11 += __float_as_int(c1.y - u1) >> 31;
            q12 += __float_as_int(c1.z - u1) >> 31;
            q13 += __float_as_int(c1.w - u1) >> 31;
            const float4 c2 = U2[kk];
            q20 += __float_as_int(c2.x - u2) >> 31;
            q21 += __float_as_int(c2.y - u2) >> 31;
            q22 += __float_as_int(c2.z - u2) >> 31;
            q23 += __float_as_int(c2.w - u2) >> 31;
            const float4 c3 = U3[kk];
            q30 += __float_as_int(c3.x - u3) >> 31;
            q31 += __float_as_int(c3.y - u3) >> 31;
            q32 += __float_as_int(c3.z - u3) >> 31;
            q33 += __float_as_int(c3.w - u3) >> 31;
        }
        const int qv0 = -((q00 + q01) + (q02 + q03));
        const int qv1 = -((q10 + q11) + (q12 + q13));
        const int qv2 = -((q20 + q21) + (q22 + q23));
        const int qv3 = -((q30 + q31) + (q32 + q33));

        acc = fmaf(u0, (float)(qv0 - pv0), acc);
        acc = fmaf(u1, (float)(qv1 - pv1), acc);
        acc = fmaf(u2, (float)(qv2 - pv2), acc);
        acc = fmaf(u3, (float)(qv3 - pv3), acc);
    }

    // ---- tail: single rows, R11 form (not hit for rows=32768) ----
    for (; row < rows; row += nwaves) {
        const int base = __builtin_amdgcn_readfirstlane(row) * N;
        const float labv = labels[base + lane];
        const float scv  = scores[base + lane];
        const float4* L4 = (const float4*)(labels + base);
        int p0 = 0, p1 = 0, p2 = 0, p3 = 0;
        #pragma unroll
        for (int kk = 0; kk < N / 4; ++kk) {
            const float4 a = L4[kk];
            p0 += __float_as_int(a.x - labv) >> 31;
            p1 += __float_as_int(a.y - labv) >> 31;
            p2 += __float_as_int(a.z - labv) >> 31;
            p3 += __float_as_int(a.w - labv) >> 31;
        }
        const int pv = -((p0 + p1) + (p2 + p3));

        const float u = fmaf(-MARGIN, (float)pv, scv);
        ubuf[w][0][lane] = u;
        asm volatile("s_waitcnt lgkmcnt(0)" ::: "memory");
        const float4* U4 = (const float4*)ubuf[w][0];
        int q0 = 0, q1 = 0, q2 = 0, q3 = 0;
        #pragma unroll
        for (int kk = 0; kk < N / 4; ++kk) {
            const float4 c = U4[kk];
            q0 += __float_as_int(c.x - u) >> 31;
            q1 += __float_as_int(c.y - u) >> 31;
            q2 += __float_as_int(c.z - u) >> 31;
            q3 += __float_as_int(c.w - u) >> 31;
        }
        const int qv = -((q0 + q1) + (q2 + q3));
        acc = fmaf(u, (float)(qv - pv), acc);
    }

    // ---- wave reduction ----
    #pragma unroll
    for (int off = 32; off > 0; off >>= 1)
        acc += __shfl_down(acc, off, 64);

    if (lane == 0) wsum[w] = acc;
    __syncthreads();
    if (threadIdx.x == 0) {
        float s = 0.0f;
        #pragma unroll
        for (int i = 0; i < WAVES_PER_BLOCK; ++i) s += wsum[i];
        partial[blockIdx.x] = s;          // plain store, no atomic, no fence
    }
}

__global__ __launch_bounds__(256) void mmrl_reduce(const float* __restrict__ partial,
                                                   float* __restrict__ out,
                                                   int npartial, float inv_rows) {
    const int t = threadIdx.x;
    float s = 0.0f;
    for (int i = t; i < npartial; i += 256)
        s += partial[i];
    #pragma unroll
    for (int off = 32; off > 0; off >>= 1)
        s += __shfl_down(s, off, 64);
    __shared__ float wsum[4];
    if ((t & 63) == 0) wsum[t >> 6] = s;
    __syncthreads();
    if (t == 0)
        out[0] = (wsum[0] + wsum[1] + wsum[2] + wsum[3]) * inv_rows;
}

extern "C" void kernel_launch(void* const* d_in, const int* in_sizes, int n_in,
                              void* d_out, int out_size, void* d_ws, size_t ws_size,
                              hipStream_t stream) {
    const float* scores = (const float*)d_in[0];
    const float* labels = (const float*)d_in[1];
    float* out = (float*)d_out;
    float* partial = (float*)d_ws;        // 2048 floats = 8 KB << ws_size
    const int rows = in_sizes[0] / N;     // 32768

    mmrl_partial<<<NBLOCKS, 256, 0, stream>>>(scores, labels, partial, rows);
    mmrl_reduce<<<1, 256, 0, stream>>>(partial, out, NBLOCKS, 1.0f / (float)rows);
}